// Round 1
// 108.871 us; speedup vs baseline: 1.0765x; 1.0765x over previous
//
#include <hip/hip_runtime.h>
#include <math.h>

// AdderNet fused forward v8: one image per block, 2 waves (128 thr) per image.
// 4096 blocks x 128 threads. Heavy stages split across waves by output channel
// to halve the per-wave critical path and double resident waves/CU.
//
// q(v) = round((v+8)*1024) u16; |q(a)-q(w)| = 1024*|a-w| (+-1). Pad = q(0).
// Integer requant (exact, validated R6): L1 q=max(10752-((S+2)>>2),8192)
//   L2 q=max(24832-((S+4)>>3),8192)   L3 q=max(26112-((S+8)>>4),8192)
//
// d_ws (uint words): QW1[96]@0      [o16][kh3][{(w0,w1),(w2,0)}]
//                    QW2[2304]@96   [m8][o32][pk9]  word=(w[o][2m][pk],w[o][2m+1][pk])
//                    QW3[2304]@2400 [m2 16][o16][pk9]
//                    QW4[720]@4704  [m8][o10][pk9]
//
// LDS (14,304 B -> 11 blocks/CU = 22 waves/CU):
//  sA1[2280]: A1 8 ch-pair planes x (15 rows, ROW STRIDE 19), ghost = q(0)
//             stride 19: stage-2 read addr = 6i+2j mod 32 -> max 3-way conflict
//             (stride 15 was 2(j-i) -> 7-way, 2.5M conflict cycles/dispatch)
//             after stage 2: part[1024]@0 [oo8][g4][w2][pos16],
//             A3[136]@1040 (stride 17), l4[40]@1176, logits(float)[10]@1216
//  sA2[1296]: A2 16 ch-pair planes x (9x9), ghost = q(0)

#if defined(__has_builtin)
#if __has_builtin(__builtin_amdgcn_sad_u16)
#define HAS_SAD 1
#endif
#endif

__device__ __forceinline__ unsigned sadu16(unsigned a, unsigned b, unsigned acc) {
#ifdef HAS_SAD
  return __builtin_amdgcn_sad_u16(a, b, acc);
#else
  int al = (int)(a & 0xFFFFu), ah = (int)(a >> 16);
  int bl = (int)(b & 0xFFFFu), bh = (int)(b >> 16);
  return acc + (unsigned)(al > bl ? al - bl : bl - al)
             + (unsigned)(ah > bh ? ah - bh : bh - ah);
#endif
}

__device__ __forceinline__ unsigned quant(float v) {
  return (unsigned)fmaf(v, 1024.0f, 8192.5f);  // v >= -8 by construction
}
__device__ __forceinline__ unsigned quantx(float v) {  // quant(v - 0.5)
  return (unsigned)fmaf(v, 1024.0f, 7680.5f);
}
__device__ __forceinline__ int imax(int a, int b) { return a > b ? a : b; }

#define QPAD 0x20002000u
#define A1STRIDE 19
#define A1PLANE 285   // 15 * 19

// ---------------- weight prep: quantize + repack into d_ws ----------------
__global__ void adder_prep(const float* __restrict__ w1, const float* __restrict__ w2,
                           const float* __restrict__ w3, const float* __restrict__ w4,
                           unsigned* __restrict__ qw) {
  int k = blockIdx.x * 256 + threadIdx.x;
  if (k < 96) {
    int o = k / 6, r = k % 6, kh = r >> 1, h = r & 1;
    const float* p = w1 + o * 9 + kh * 3;
    qw[k] = h ? quant(p[2]) : (quant(p[0]) | (quant(p[1]) << 16));
  } else if (k < 2400) {
    int k2 = k - 96, m = k2 / 288, r = k2 % 288, o = r / 9, pk = r % 9;
    int s = o * 144 + 2 * m * 9 + pk;
    qw[k] = quant(w2[s]) | (quant(w2[s + 9]) << 16);
  } else if (k < 4704) {
    int k3 = k - 2400, m2 = k3 / 144, r = k3 % 144, o = r / 9, pk = r % 9;
    int s = o * 288 + 2 * m2 * 9 + pk;
    qw[k] = quant(w3[s]) | (quant(w3[s + 9]) << 16);
  } else if (k < 5424) {
    int k4 = k - 4704, m = k4 / 90, r = k4 % 90, o = r / 9, pk = r % 9;
    int s = o * 144 + 2 * m * 9 + pk;
    qw[k] = quant(w4[s]) | (quant(w4[s + 9]) << 16);
  }
}

__global__ __launch_bounds__(128, 4) void adder_main(
    const float* __restrict__ gx,
    const unsigned* __restrict__ qw,
    float* __restrict__ gout)
{
  __shared__ __align__(16) unsigned sA1[2280];
  __shared__ __align__(16) unsigned sA2[1296];

  const int t = threadIdx.x;
  const int l = t & 63;                                   // lane in wave
  const int wu = __builtin_amdgcn_readfirstlane(t >> 6);  // wave id, in SGPR so
                                                          // weight addrs stay s_load
  const int b = blockIdx.x;
  const float* img = gx + (size_t)b * 784;

  // ---------------- stage 0: ghost borders (A1 and A2) ----------------
  for (int k = t; k < 448; k += 128) {       // A1: 8 planes x 56 perimeter cells
    int plane = k / 56, c = k % 56;
    int y, x;
    if (c < 15)      { y = 0;      x = c; }
    else if (c < 30) { y = 14;     x = c - 15; }
    else if (c < 43) { y = c - 29; x = 0; }
    else             { y = c - 42; x = 14; }
    sA1[plane * A1PLANE + y * A1STRIDE + x] = QPAD;
  }
  for (int k = t; k < 512; k += 128) {       // A2: 16 planes x 32 perimeter cells
    int plane = k >> 5, c = k & 31;
    int y, x;
    if (c < 9)       { y = 0; x = c; }
    else if (c < 18) { y = 8; x = c - 9; }
    else if (c < 25) { y = c - 17; x = 0; }
    else             { y = c - 24; x = 8; }
    sA2[plane * 81 + y * 9 + x] = QPAD;
  }

  // ------- stage 1: L1 [16,13,13]; wave w does op-pairs w*4..w*4+3 -------
  if (l < 52) {
    const int i = l >> 2, jq = l & 3;       // output rows i, cols j=4jq+jj
    unsigned r[3][5], mw[3][4];
#pragma unroll
    for (int kh = 0; kh < 3; ++kh) {
      const float* rp = img + (2 * i + kh) * 28 + 8 * jq;
      float4 A = *(const float4*)(rp);
      float4 B = *(const float4*)(rp + 4);
      float2 C = *(const float2*)(rp + 8);
      r[kh][0] = quantx(A.x) | (quantx(A.y) << 16);
      r[kh][1] = quantx(A.z) | (quantx(A.w) << 16);
      r[kh][2] = quantx(B.x) | (quantx(B.y) << 16);
      r[kh][3] = quantx(B.z) | (quantx(B.w) << 16);
      r[kh][4] = quantx(C.x) | (quantx(C.y) << 16);
#pragma unroll
      for (int c = 0; c < 4; ++c) mw[kh][c] = r[kh][c + 1] & 0xFFFFu;
    }
#pragma unroll 1
    for (int opp = 0; opp < 4; ++opp) {     // this wave's output-channel pairs
      const int op = wu * 4 + opp;
      const unsigned* w = qw + op * 12;     // uniform -> s_load
      unsigned a0[4], a1[4];
#pragma unroll
      for (int jj = 0; jj < 4; ++jj) { a0[jj] = 0u; a1[jj] = 0u; }
#pragma unroll
      for (int kh = 0; kh < 3; ++kh) {
        unsigned wa01 = w[kh * 2], wa2 = w[kh * 2 + 1];
        unsigned wb01 = w[6 + kh * 2], wb2 = w[6 + kh * 2 + 1];
#pragma unroll
        for (int jj = 0; jj < 4; ++jj) {
          a0[jj] = sadu16(r[kh][jj], wa01, a0[jj]);
          a0[jj] = sadu16(mw[kh][jj], wa2, a0[jj]);
          a1[jj] = sadu16(r[kh][jj], wb01, a1[jj]);
          a1[jj] = sadu16(mw[kh][jj], wb2, a1[jj]);
        }
      }
      unsigned* dst = sA1 + op * A1PLANE + (i + 1) * A1STRIDE + 4 * jq + 1;
#pragma unroll
      for (int jj = 0; jj < 4; ++jj) {
        if (4 * jq + jj < 13) {
          int q0 = imax(10752 - (int)((a0[jj] + 2u) >> 2), 8192);
          int q1 = imax(10752 - (int)((a1[jj] + 2u) >> 2), 8192);
          dst[jj] = (unsigned)q0 | ((unsigned)q1 << 16);
        }
      }
    }
  }
  __syncthreads();

  // ------- stage 2: L2 [32,7,7]; wave w does o = w*16..w*16+15 -------
  if (l < 49) {
    const int i = l / 7, j = l % 7;
    unsigned acc[16];
#pragma unroll
    for (int o = 0; o < 16; ++o) acc[o] = 0u;
    const unsigned* qw2 = qw + 96 + wu * 144;  // o-offset: wu*16*9, uniform
#pragma unroll 1
    for (int m = 0; m < 8; ++m) {
      const unsigned* plane = sA1 + m * A1PLANE + 2 * j;
      unsigned p[3][3];
#pragma unroll
      for (int kh = 0; kh < 3; ++kh)
#pragma unroll
        for (int c = 0; c < 3; ++c)
          p[kh][c] = plane[(2 * i + kh) * A1STRIDE + c];
      const unsigned* wm = qw2 + m * 288;   // uniform -> s_load
#pragma unroll
      for (int o = 0; o < 16; ++o) {
        const unsigned* w9 = wm + o * 9;
        unsigned a = acc[o];
#pragma unroll
        for (int kh = 0; kh < 3; ++kh)
#pragma unroll
          for (int c = 0; c < 3; ++c)
            a = sadu16(p[kh][c], w9[kh * 3 + c], a);
        acc[o] = a;
      }
    }
#pragma unroll
    for (int m2 = 0; m2 < 8; ++m2) {        // global ch-pair = wu*8 + m2
      int q0 = imax(24832 - (int)((acc[2 * m2] + 4u) >> 3), 8192);
      int q1 = imax(24832 - (int)((acc[2 * m2 + 1] + 4u) >> 3), 8192);
      sA2[(wu * 8 + m2) * 81 + (i + 1) * 9 + (j + 1)] = (unsigned)q0 | ((unsigned)q1 << 16);
    }
  }
  __syncthreads();

  // ------- stage 3: L3 [16,4,4]; wave w -> o = w*8..w*8+7, m2 split 4-way
  //         across lane groups g (4 m2 each), partials reduced via LDS -------
  {
    const int pos = l & 15, g = l >> 4;     // g in 0..3
    const int i = pos >> 2, j = pos & 3;
    unsigned acc[8];
#pragma unroll
    for (int o = 0; o < 8; ++o) acc[o] = 0u;
    const unsigned* qw3 = qw + 2400 + wu * 72;
#pragma unroll 1
    for (int mm = 0; mm < 4; ++mm) {
      const int m2 = g * 4 + mm;
      const unsigned* plane = sA2 + m2 * 81 + 2 * j;
      unsigned p[3][3];
#pragma unroll
      for (int kh = 0; kh < 3; ++kh)
#pragma unroll
        for (int c = 0; c < 3; ++c)
          p[kh][c] = plane[(2 * i + kh) * 9 + c];
      const unsigned* ws = qw3 + m2 * 144;  // per-lane (g) -> vector loads, L1-hot
#pragma unroll
      for (int oo = 0; oo < 8; ++oo) {
        const unsigned* w9 = ws + oo * 9;
        unsigned a = acc[oo];
#pragma unroll
        for (int kh = 0; kh < 3; ++kh)
#pragma unroll
          for (int c = 0; c < 3; ++c)
            a = sadu16(p[kh][c], w9[kh * 3 + c], a);
        acc[oo] = a;
      }
    }
    // A1 dead now; partials at sA1[0..1023], layout [oo8][g4][w2][pos16]
#pragma unroll
    for (int oo = 0; oo < 8; ++oo)
      sA1[oo * 128 + g * 32 + wu * 16 + pos] = acc[oo];
  }
  __syncthreads();

  // reduce 4 g-partials -> A3 pair words [m8][pos16] @ sA1[1040..], stride 17
  {
    const int m = t >> 4, pos = t & 15;     // m = output ch-pair 0..7
    const int ww = m >> 2;                  // wave that computed this pair
    const int oo0 = 2 * m - ww * 8;
    unsigned s0 = 0u, s1 = 0u;
#pragma unroll
    for (int g = 0; g < 4; ++g) {
      s0 += sA1[oo0 * 128 + g * 32 + ww * 16 + pos];
      s1 += sA1[(oo0 + 1) * 128 + g * 32 + ww * 16 + pos];
    }
    int q0 = imax(26112 - (int)((s0 + 8u) >> 4), 8192);
    int q1 = imax(26112 - (int)((s1 + 8u) >> 4), 8192);
    sA1[1040 + m * 17 + pos] = (unsigned)q0 | ((unsigned)q1 << 16);
  }
  __syncthreads();

  // ---------------- stage 4: L4 + log_softmax ----------------
  if (t < 40) {
    const int o = t % 10, mq = t / 10;
    const unsigned* qw4 = qw + 4704;
    unsigned acc = 0u;
#pragma unroll
    for (int mm = 0; mm < 2; ++mm) {
      const int m = mq * 2 + mm;
      const unsigned* a3 = sA1 + 1040 + m * 17;
      const unsigned* w9 = qw4 + (m * 10 + o) * 9;  // per-lane -> vector loads
#pragma unroll
      for (int kh = 0; kh < 3; ++kh)
#pragma unroll
        for (int kw = 0; kw < 3; ++kw)
          acc = sadu16(a3[kh * 4 + kw], w9[kh * 3 + kw], acc);
    }
    sA1[1176 + t] = acc;
  }
  __syncthreads();
  if (t < 10) {
    unsigned s = sA1[1176 + t] + sA1[1186 + t] + sA1[1196 + t] + sA1[1206 + t];
    ((float*)sA1)[1216 + t] = -(float)s * (1.0f / 1024.0f);
  }
  __syncthreads();
  if (t < 10) {
    const float* lg = (const float*)sA1 + 1216;
    float mx = lg[0];
#pragma unroll
    for (int k = 1; k < 10; ++k) mx = fmaxf(mx, lg[k]);
    float sum = 0.0f;
#pragma unroll
    for (int k = 0; k < 10; ++k) sum += __expf(lg[k] - mx);
    gout[(size_t)b * 10 + t] = lg[t] - mx - __logf(sum);
  }
}

extern "C" void kernel_launch(void* const* d_in, const int* in_sizes, int n_in,
                              void* d_out, int out_size, void* d_ws, size_t ws_size,
                              hipStream_t stream) {
  const float* x  = (const float*)d_in[0];
  const float* w1 = (const float*)d_in[1];
  const float* w2 = (const float*)d_in[2];
  const float* w3 = (const float*)d_in[3];
  const float* w4 = (const float*)d_in[4];
  unsigned* qw = (unsigned*)d_ws;           // 5424 words = 21.7 KB
  float* out = (float*)d_out;
  adder_prep<<<22, 256, 0, stream>>>(w1, w2, w3, w4, qw);
  adder_main<<<4096, 128, 0, stream>>>(x, qw, out);
}